// Round 11
// baseline (450.857 us; speedup 1.0000x reference)
//
#include <hip/hip_runtime.h>

typedef __attribute__((ext_vector_type(8))) short bf16x8;
typedef __attribute__((ext_vector_type(4))) float f32x4;

static __device__ __forceinline__ short f2bf(float f) {
  union { float f; unsigned u; } v; v.f = f;
  unsigned r = v.u + 0x7fffu + ((v.u >> 16) & 1u);
  return (short)(r >> 16);
}
static __device__ __forceinline__ float bf2f(short s) {
  union { unsigned u; float f; } v; v.u = ((unsigned)(unsigned short)s) << 16;
  return v.f;
}

#define GLOBAL_AS(p) ((const __attribute__((address_space(1))) void*)(p))
#define LDS_AS(p)    ((__attribute__((address_space(3))) void*)(p))

// ---------------------------------------------------------------------------
// Batched prep (R9 config: proven 437us). BW-bound x0 conversion first (z<8),
// zeroing z==8, tiny latency-bound transposes last (z>=9).
struct WD { const float* W; short* Wt; int ldt; int koff; int Nn; };
struct PrepArgs {
  WD d[12];
  const float* x0; short* xb0; int n8;
  int* deg; int* cursor; int ndeg; float* stats; int nstats;
};

__global__ void prep_kernel(PrepArgs P) {
  int z = blockIdx.z;
  if (z < 8) {
    int gtid = (z * 256 + blockIdx.y * 16 + blockIdx.x) * 256 + threadIdx.x;
    int wv = gtid >> 6, lane = gtid & 63;
    const float4* __restrict__ src = (const float4*)P.x0;
    short4* __restrict__ dst = (short4*)P.xb0;
    int n4 = P.n8 * 2;
    for (int b = wv * 128 + lane; b < n4; b += 1048576) {
      float4 a = src[b];
      float4 c = src[b + 64];
      short4 o1; o1.x = f2bf(a.x); o1.y = f2bf(a.y); o1.z = f2bf(a.z); o1.w = f2bf(a.w);
      short4 o2; o2.x = f2bf(c.x); o2.y = f2bf(c.y); o2.z = f2bf(c.z); o2.w = f2bf(c.w);
      dst[b] = o1;
      dst[b + 64] = o2;
    }
  } else if (z == 8) {
    int base = (blockIdx.y * 16 + blockIdx.x) * 256 + threadIdx.x;
    for (int i = base; i < P.ndeg; i += 65536) { P.deg[i] = 0; P.cursor[i] = 0; }
    for (int i = base; i < P.nstats; i += 65536) P.stats[i] = 0.f;
  } else {
    __shared__ float tile[32][33];
    const WD dd = P.d[z - 9];
    int kb = blockIdx.x * 32, nb = blockIdx.y * 32;
    if (nb >= dd.Nn) return;
    int tx = threadIdx.x & 31, ty = threadIdx.x >> 5;
#pragma unroll
    for (int j = 0; j < 4; ++j) {
      int k = kb + ty + 8 * j;
      tile[ty + 8 * j][tx] = dd.W[(size_t)k * dd.Nn + nb + tx];
    }
    __syncthreads();
#pragma unroll
    for (int j = 0; j < 4; ++j) {
      int n = nb + ty + 8 * j;
      dd.Wt[(size_t)n * dd.ldt + dd.koff + kb + tx] = f2bf(tile[tx][ty + 8 * j]);
    }
  }
}

// ---------------------------------------------------------------------------
// CSR build, all 3 layers.
struct L3s { const int* ei[3]; int E[3]; int dbase[3]; int ebase[3]; };

__global__ void deg_all_kernel(L3s L, int* __restrict__ deg) {
  int g = blockIdx.x * 256 + threadIdx.x;
  int l = 0, e = g;
  while (l < 3 && e >= L.E[l]) { e -= L.E[l]; ++l; }
  if (l >= 3) return;
  int d = L.ei[l][L.E[l] + e];
  atomicAdd(&deg[L.dbase[l] + d], 1);
}

__global__ void scan_all_kernel(L3s Ln, const int* __restrict__ deg, int* __restrict__ offs) {
  __shared__ int sums[257];
  int l = blockIdx.x;
  int n = Ln.E[l];
  const int* dg = deg + Ln.dbase[l];
  int* of = offs + Ln.dbase[l];
  int t = threadIdx.x;
  int per = (n + 255) / 256;
  int b = t * per, e = min(b + per, n);
  int s = 0;
  for (int i = b; i < e; ++i) s += dg[i];
  sums[t] = s;
  __syncthreads();
  if (t == 0) {
    int acc = 0;
    for (int i = 0; i < 256; ++i) { int v = sums[i]; sums[i] = acc; acc += v; }
    sums[256] = acc;
  }
  __syncthreads();
  int acc = sums[t];
  for (int i = b; i < e; ++i) { of[i] = acc; acc += dg[i]; }
  if (t == 255) of[n] = sums[256];
}

__global__ void fill_all_kernel(L3s L, const int* __restrict__ offs,
                                int* __restrict__ cursor, int* __restrict__ csr) {
  int g = blockIdx.x * 256 + threadIdx.x;
  int l = 0, e = g;
  while (l < 3 && e >= L.E[l]) { e -= L.E[l]; ++l; }
  if (l >= 3) return;
  int d = L.ei[l][L.E[l] + e];
  int p = atomicAdd(&cursor[L.dbase[l] + d], 1);
  csr[L.ebase[l] + offs[L.dbase[l] + d] + p] = L.ei[l][e];
}

// ---------------------------------------------------------------------------
// Gather aggregation, wave-per-node, 4-deep unroll. Mean half only.
__global__ void aggregate_kernel(const short* __restrict__ xb, const int* __restrict__ csr,
                                 const int* __restrict__ offs, short* __restrict__ A,
                                 int n_dst) {
  int node = blockIdx.x * 4 + (threadIdx.x >> 6);
  if (node >= n_dst) return;
  int lane = threadIdx.x & 63;
  const short* xp = xb + lane * 8;
  int s0 = offs[node], s1 = offs[node + 1];
  float a[8];
#pragma unroll
  for (int j = 0; j < 8; ++j) a[j] = 0.f;
  int e = s0;
  for (; e + 3 < s1; e += 4) {
    bf16x8 v0 = *(const bf16x8*)(xp + (size_t)csr[e] * 512);
    bf16x8 v1 = *(const bf16x8*)(xp + (size_t)csr[e + 1] * 512);
    bf16x8 v2 = *(const bf16x8*)(xp + (size_t)csr[e + 2] * 512);
    bf16x8 v3 = *(const bf16x8*)(xp + (size_t)csr[e + 3] * 512);
#pragma unroll
    for (int j = 0; j < 8; ++j) a[j] += (bf2f(v0[j]) + bf2f(v1[j])) + (bf2f(v2[j]) + bf2f(v3[j]));
  }
  for (; e < s1; ++e) {
    bf16x8 v0 = *(const bf16x8*)(xp + (size_t)csr[e] * 512);
#pragma unroll
    for (int j = 0; j < 8; ++j) a[j] += bf2f(v0[j]);
  }
  float inv = (s1 > s0) ? 1.0f / (float)(s1 - s0) : 0.0f;
  bf16x8 o;
#pragma unroll
  for (int j = 0; j < 8; ++j) o[j] = f2bf(a[j] * inv);
  *(bf16x8*)(A + (size_t)node * 512 + lane * 8) = o;
}

// ---------------------------------------------------------------------------
// 128x128 GEMM with dual-descriptor dispatch (layer-0 sage + res share one
// grid; res backfills sage's block-quantization tail).
struct G128 {
  const short* Am; const short* Ax;
  const short* Bt; int ldb;
  short* hC; float* fC; int ldc;
  int M; int K;
  const float* bias; float* stats;
  int gm; int gn;
};

__global__ __launch_bounds__(256, 4)
void gemm128_dual_kernel(G128 d0, G128 d1, int nb0) {
  __shared__ short lds[16384];
  short* As = lds;
  short* Bs = lds + 8192;
  const bool second = (int)blockIdx.x >= nb0;
  const G128& D = second ? d1 : d0;
  const int id = (int)blockIdx.x - (second ? nb0 : 0);
  const int g = id >> 3;
  const int bn = g % D.gn;
  const int bm = (g / D.gn) * 8 + (id & 7);
  if (bm >= D.gm) return;
  const int tid = threadIdx.x;
  const int wid = tid >> 6;
  const int lane = tid & 63;
  const int lm = lane & 15;
  const int quad = lane >> 4;
  const int wr = wid >> 1, wc = wid & 1;
  const int srow = lane >> 3;
  const int kswz = (((lane & 7) ^ srow) << 3);
  const int M = D.M;

  f32x4 acc[4][4];
#pragma unroll
  for (int i = 0; i < 4; ++i)
#pragma unroll
    for (int j = 0; j < 4; ++j) acc[i][j] = (f32x4)0.f;

  for (int k0 = 0; k0 < D.K; k0 += 64) {
    const short* Aptr = (k0 < 512) ? D.Am : D.Ax;
    int kloc = k0 & 511;
#pragma unroll
    for (int j = 0; j < 4; ++j) {
      int ch = wid * 4 + j;
      int arow = bm * 128 + ch * 8 + srow;
      arow = arow < M ? arow : M - 1;
      const short* ga = Aptr + (size_t)arow * 512 + kloc + kswz;
      __builtin_amdgcn_global_load_lds(GLOBAL_AS(ga), LDS_AS(As + ch * 512), 16, 0, 0);
      int brow = bn * 128 + ch * 8 + srow;
      const short* gb = D.Bt + (size_t)brow * D.ldb + k0 + kswz;
      __builtin_amdgcn_global_load_lds(GLOBAL_AS(gb), LDS_AS(Bs + ch * 512), 16, 0, 0);
    }
    __syncthreads();
#pragma unroll
    for (int ks = 0; ks < 2; ++ks) {
      bf16x8 af[4], bfr[4];
      int xo = ((ks * 4 + quad) ^ (lm & 7)) * 8;
#pragma unroll
      for (int mi = 0; mi < 4; ++mi)
        af[mi] = *(const bf16x8*)(As + (wr * 64 + mi * 16 + lm) * 64 + xo);
#pragma unroll
      for (int ni = 0; ni < 4; ++ni)
        bfr[ni] = *(const bf16x8*)(Bs + (wc * 64 + ni * 16 + lm) * 64 + xo);
#pragma unroll
      for (int mi = 0; mi < 4; ++mi)
#pragma unroll
        for (int ni = 0; ni < 4; ++ni)
          acc[mi][ni] = __builtin_amdgcn_mfma_f32_16x16x32_bf16(af[mi], bfr[ni], acc[mi][ni], 0, 0, 0);
    }
    __syncthreads();
  }

#pragma unroll
  for (int mi = 0; mi < 4; ++mi) {
#pragma unroll
    for (int ni = 0; ni < 4; ++ni) {
      int gcol = bn * 128 + wc * 64 + ni * 16 + lm;
      float bv = D.bias ? D.bias[gcol] : 0.f;
#pragma unroll
      for (int r2 = 0; r2 < 4; ++r2) {
        int grow = bm * 128 + wr * 64 + mi * 16 + quad * 4 + r2;
        if (grow < M) {
          float val = acc[mi][ni][r2] + bv;
          if (D.hC) D.hC[(size_t)grow * D.ldc + gcol] = f2bf(val);
          else      D.fC[(size_t)grow * D.ldc + gcol] = val;
        }
      }
    }
  }

  if (D.stats) {
    float* s1 = (float*)lds;
    float* s2 = s1 + 128;
    if (tid < 128) { s1[tid] = 0.f; s2[tid] = 0.f; }
    __syncthreads();
#pragma unroll
    for (int ni = 0; ni < 4; ++ni) {
      int cloc = wc * 64 + ni * 16 + lm;
      float p1 = 0.f, p2 = 0.f;
#pragma unroll
      for (int mi = 0; mi < 4; ++mi)
#pragma unroll
        for (int r2 = 0; r2 < 4; ++r2) {
          int grow = bm * 128 + wr * 64 + mi * 16 + quad * 4 + r2;
          if (grow < M) {
            float v = acc[mi][ni][r2];
            p1 += v; p2 += v * v;
          }
        }
      atomicAdd(&s1[cloc], p1);
      atomicAdd(&s2[cloc], p2);
    }
    __syncthreads();
    if (tid < 128) {
      int gcol = bn * 128 + tid;
      atomicAdd(&D.stats[gcol], s1[tid]);
      atomicAdd(&D.stats[512 + gcol], s2[tid]);
    }
  }
}

// ---------------------------------------------------------------------------
// BM=64 GEMM for small-M dispatches (M<=15000).
__global__ __launch_bounds__(256, 4)
void sage_gemm64_kernel(const short* __restrict__ A0, const short* __restrict__ A1,
                        const short* __restrict__ A2, const short* __restrict__ A3,
                        const short* __restrict__ Bt, int ldb,
                        short* __restrict__ hC, float* __restrict__ fC, int ldc,
                        int M, int K, const float* __restrict__ bias,
                        float* __restrict__ stats, int gm, int gn) {
  __shared__ short lds[12288];   // As 64x64 (8KB) + Bs 128x64 (16KB)
  short* As = lds;
  short* Bs = lds + 4096;
  const int id = blockIdx.x;
  const int g = id >> 3;
  const int bn = g % gn;
  const int bm = (g / gn) * 8 + (id & 7);
  if (bm >= gm) return;
  const int tid = threadIdx.x;
  const int wid = tid >> 6;
  const int lane = tid & 63;
  const int lm = lane & 15;
  const int quad = lane >> 4;
  const int srow = lane >> 3;
  const int kswz = (((lane & 7) ^ srow) << 3);
  const short* Aps[4] = {A0, A1, A2, A3};

  f32x4 acc[4][2];
#pragma unroll
  for (int i = 0; i < 4; ++i)
#pragma unroll
    for (int j = 0; j < 2; ++j) acc[i][j] = (f32x4)0.f;

  for (int k0 = 0; k0 < K; k0 += 64) {
    const short* Aptr = Aps[k0 >> 9];
    int kloc = k0 & 511;
#pragma unroll
    for (int j = 0; j < 6; ++j) {
      int ch = wid * 6 + j;
      if (ch < 8) {
        int arow = bm * 64 + ch * 8 + srow;
        arow = arow < M ? arow : M - 1;
        const short* ga = Aptr + (size_t)arow * 512 + kloc + kswz;
        __builtin_amdgcn_global_load_lds(GLOBAL_AS(ga), LDS_AS(As + ch * 512), 16, 0, 0);
      } else {
        int bc = ch - 8;
        int brow = bn * 128 + bc * 8 + srow;
        const short* gb = Bt + (size_t)brow * ldb + k0 + kswz;
        __builtin_amdgcn_global_load_lds(GLOBAL_AS(gb), LDS_AS(Bs + bc * 512), 16, 0, 0);
      }
    }
    __syncthreads();
#pragma unroll
    for (int ks = 0; ks < 2; ++ks) {
      bf16x8 af[4], bfr[2];
      int xo = ((ks * 4 + quad) ^ (lm & 7)) * 8;
#pragma unroll
      for (int mi = 0; mi < 4; ++mi)
        af[mi] = *(const bf16x8*)(As + (mi * 16 + lm) * 64 + xo);
#pragma unroll
      for (int ni = 0; ni < 2; ++ni)
        bfr[ni] = *(const bf16x8*)(Bs + (wid * 32 + ni * 16 + lm) * 64 + xo);
#pragma unroll
      for (int mi = 0; mi < 4; ++mi)
#pragma unroll
        for (int ni = 0; ni < 2; ++ni)
          acc[mi][ni] = __builtin_amdgcn_mfma_f32_16x16x32_bf16(af[mi], bfr[ni], acc[mi][ni], 0, 0, 0);
    }
    __syncthreads();
  }

#pragma unroll
  for (int mi = 0; mi < 4; ++mi) {
#pragma unroll
    for (int ni = 0; ni < 2; ++ni) {
      int gcol = bn * 128 + wid * 32 + ni * 16 + lm;
      float bv = bias ? bias[gcol] : 0.f;
#pragma unroll
      for (int r2 = 0; r2 < 4; ++r2) {
        int grow = bm * 64 + mi * 16 + quad * 4 + r2;
        if (grow < M) {
          float val = acc[mi][ni][r2] + bv;
          if (hC) hC[(size_t)grow * ldc + gcol] = f2bf(val);
          else    fC[(size_t)grow * ldc + gcol] = val;
        }
      }
    }
  }

  if (stats) {
    float* s1 = (float*)lds;
    float* s2 = s1 + 128;
    if (tid < 128) { s1[tid] = 0.f; s2[tid] = 0.f; }
    __syncthreads();
#pragma unroll
    for (int ni = 0; ni < 2; ++ni) {
      int cloc = wid * 32 + ni * 16 + lm;
      float p1 = 0.f, p2 = 0.f;
#pragma unroll
      for (int mi = 0; mi < 4; ++mi)
#pragma unroll
        for (int r2 = 0; r2 < 4; ++r2) {
          int grow = bm * 64 + mi * 16 + quad * 4 + r2;
          if (grow < M) {
            float v = acc[mi][ni][r2];
            p1 += v; p2 += v * v;
          }
        }
      atomicAdd(&s1[cloc], p1);
      atomicAdd(&s2[cloc], p2);
    }
    __syncthreads();
    if (tid < 128) {
      int gcol = bn * 128 + tid;
      atomicAdd(&stats[gcol], s1[tid]);
      atomicAdd(&stats[512 + gcol], s2[tid]);
    }
  }
}

// ---------------------------------------------------------------------------
// Fused head-2: z2 = z1b @ W2t + b2 followed by log_softmax, one kernel.
// BM=64, BN=256 (full output width) so each block owns complete rows;
// row-reduce: per-quad shfl_xor (16 lanes) then cross-wave LDS [4][64].
// M=8000 = 125*64 exactly (no bounds checks). Verified in R10 (absmax ok).
__global__ __launch_bounds__(256, 4)
void head2_kernel(const short* __restrict__ A, const short* __restrict__ Bt,
                  const float* __restrict__ bias, float* __restrict__ outp) {
  __shared__ short lds[20480];   // As 64x64 (8KB) + Bs 256x64 (32KB)
  short* As = lds;
  short* Bs = lds + 4096;
  const int bm = blockIdx.x;
  const int tid = threadIdx.x;
  const int wid = tid >> 6;
  const int lane = tid & 63;
  const int lm = lane & 15;
  const int quad = lane >> 4;
  const int srow = lane >> 3;
  const int kswz = (((lane & 7) ^ srow) << 3);

  f32x4 acc[4][4];
#pragma unroll
  for (int i = 0; i < 4; ++i)
#pragma unroll
    for (int j = 0; j < 4; ++j) acc[i][j] = (f32x4)0.f;

  for (int k0 = 0; k0 < 512; k0 += 64) {
    // 40 chunks of 8 rows: 0-7 -> A (64 rows), 8-39 -> B (256 rows); 10/wave.
#pragma unroll
    for (int j = 0; j < 10; ++j) {
      int ch = wid * 10 + j;
      if (ch < 8) {
        int arow = bm * 64 + ch * 8 + srow;
        const short* ga = A + (size_t)arow * 512 + k0 + kswz;
        __builtin_amdgcn_global_load_lds(GLOBAL_AS(ga), LDS_AS(As + ch * 512), 16, 0, 0);
      } else {
        int bc = ch - 8;
        int brow = bc * 8 + srow;
        const short* gb = Bt + (size_t)brow * 512 + k0 + kswz;
        __builtin_amdgcn_global_load_lds(GLOBAL_AS(gb), LDS_AS(Bs + bc * 512), 16, 0, 0);
      }
    }
    __syncthreads();
#pragma unroll
    for (int ks = 0; ks < 2; ++ks) {
      bf16x8 af[4], bfr[4];
      int xo = ((ks * 4 + quad) ^ (lm & 7)) * 8;
#pragma unroll
      for (int mi = 0; mi < 4; ++mi)
        af[mi] = *(const bf16x8*)(As + (mi * 16 + lm) * 64 + xo);
#pragma unroll
      for (int ni = 0; ni < 4; ++ni)
        bfr[ni] = *(const bf16x8*)(Bs + (wid * 64 + ni * 16 + lm) * 64 + xo);
#pragma unroll
      for (int mi = 0; mi < 4; ++mi)
#pragma unroll
        for (int ni = 0; ni < 4; ++ni)
          acc[mi][ni] = __builtin_amdgcn_mfma_f32_16x16x32_bf16(af[mi], bfr[ni], acc[mi][ni], 0, 0, 0);
    }
    __syncthreads();
  }

  float bv[4];
#pragma unroll
  for (int ni = 0; ni < 4; ++ni) bv[ni] = bias[wid * 64 + ni * 16 + lm];

  float* red = (float*)lds;      // [0,256): per-wave row max; [256,512): row sum
  // Phase 1: per-row max (includes bias), quad-wide shfl then LDS.
#pragma unroll
  for (int mi = 0; mi < 4; ++mi)
#pragma unroll
    for (int r2 = 0; r2 < 4; ++r2) {
      float m = acc[mi][0][r2] + bv[0];
#pragma unroll
      for (int ni = 1; ni < 4; ++ni) m = fmaxf(m, acc[mi][ni][r2] + bv[ni]);
      m = fmaxf(m, __shfl_xor(m, 1, 64));
      m = fmaxf(m, __shfl_xor(m, 2, 64));
      m = fmaxf(m, __shfl_xor(m, 4, 64));
      m = fmaxf(m, __shfl_xor(m, 8, 64));
      if (lm == 0) red[wid * 64 + mi * 16 + quad * 4 + r2] = m;
    }
  __syncthreads();
  // Phase 2: final max, exp-sum per row.
  float fm[4][4];
#pragma unroll
  for (int mi = 0; mi < 4; ++mi)
#pragma unroll
    for (int r2 = 0; r2 < 4; ++r2) {
      int row = mi * 16 + quad * 4 + r2;
      float m = fmaxf(fmaxf(red[row], red[64 + row]),
                      fmaxf(red[128 + row], red[192 + row]));
      fm[mi][r2] = m;
      float s = 0.f;
#pragma unroll
      for (int ni = 0; ni < 4; ++ni) s += __expf(acc[mi][ni][r2] + bv[ni] - m);
      s += __shfl_xor(s, 1, 64);
      s += __shfl_xor(s, 2, 64);
      s += __shfl_xor(s, 4, 64);
      s += __shfl_xor(s, 8, 64);
      if (lm == 0) red[256 + wid * 64 + row] = s;
    }
  __syncthreads();
  // Phase 3: write log-softmax.
#pragma unroll
  for (int mi = 0; mi < 4; ++mi)
#pragma unroll
    for (int r2 = 0; r2 < 4; ++r2) {
      int row = mi * 16 + quad * 4 + r2;
      float s = red[256 + row] + red[320 + row] + red[384 + row] + red[448 + row];
      float ls = __logf(s);
#pragma unroll
      for (int ni = 0; ni < 4; ++ni) {
        int gcol = wid * 64 + ni * 16 + lm;
        outp[(size_t)(bm * 64 + row) * 256 + gcol] =
            acc[mi][ni][r2] + bv[ni] - fm[mi][r2] - ls;
      }
    }
}

// ---------------------------------------------------------------------------
// x_out(bf16) = leaky(BN(h_bf16; stats)) + (rbuf_bf16 + res_b | xdst_bf16).
__global__ void apply_kernel(const short* __restrict__ h, const float* __restrict__ stats,
                             const float* __restrict__ g, const float* __restrict__ b,
                             const short* __restrict__ r, const float* __restrict__ res_b,
                             const short* __restrict__ xdst, short* __restrict__ outp,
                             int n, float inv_n) {
  int i = blockIdx.x;
  int c = threadIdx.x * 4;
  short4 hb = *(const short4*)(h + (size_t)i * 512 + c);
  float4 s1 = *(const float4*)(stats + c);
  float4 s2 = *(const float4*)(stats + 512 + c);
  float4 gv = *(const float4*)(g + c);
  float4 bv = *(const float4*)(b + c);
  float mux = s1.x * inv_n, muy = s1.y * inv_n, muz = s1.z * inv_n, muw = s1.w * inv_n;
  float rsx = rsqrtf(s2.x * inv_n - mux * mux + 1e-5f);
  float rsy = rsqrtf(s2.y * inv_n - muy * muy + 1e-5f);
  float rsz = rsqrtf(s2.z * inv_n - muz * muz + 1e-5f);
  float rsw = rsqrtf(s2.w * inv_n - muw * muw + 1e-5f);
  float4 o;
  o.x = (bf2f(hb.x) - mux) * rsx * gv.x + bv.x;
  o.y = (bf2f(hb.y) - muy) * rsy * gv.y + bv.y;
  o.z = (bf2f(hb.z) - muz) * rsz * gv.z + bv.z;
  o.w = (bf2f(hb.w) - muw) * rsw * gv.w + bv.w;
  o.x = o.x >= 0.f ? o.x : 0.01f * o.x;
  o.y = o.y >= 0.f ? o.y : 0.01f * o.y;
  o.z = o.z >= 0.f ? o.z : 0.01f * o.z;
  o.w = o.w >= 0.f ? o.w : 0.01f * o.w;
  if (r) {
    short4 rv = *(const short4*)(r + (size_t)i * 512 + c);
    float4 rb = *(const float4*)(res_b + c);
    o.x += bf2f(rv.x) + rb.x; o.y += bf2f(rv.y) + rb.y;
    o.z += bf2f(rv.z) + rb.z; o.w += bf2f(rv.w) + rb.w;
  } else {
    short4 xv = *(const short4*)(xdst + (size_t)i * 512 + c);
    o.x += bf2f(xv.x); o.y += bf2f(xv.y); o.z += bf2f(xv.z); o.w += bf2f(xv.w);
  }
  short4 ov;
  ov.x = f2bf(o.x); ov.y = f2bf(o.y); ov.z = f2bf(o.z); ov.w = f2bf(o.w);
  *(short4*)(outp + (size_t)i * 512 + c) = ov;
}

// ---------------------------------------------------------------------------
extern "C" void kernel_launch(void* const* d_in, const int* in_sizes, int n_in,
                              void* d_out, int out_size, void* d_ws, size_t ws_size,
                              hipStream_t stream) {
  const float* x0 = (const float*)d_in[0];
  const int* eis[3] = {(const int*)d_in[1], (const int*)d_in[2], (const int*)d_in[3]};
  const float* Wl[3] = {(const float*)d_in[4], (const float*)d_in[8], (const float*)d_in[12]};
  const float* Wr[3] = {(const float*)d_in[5], (const float*)d_in[9], (const float*)d_in[13]};
  const float* gg[3] = {(const float*)d_in[6], (const float*)d_in[10], (const float*)d_in[14]};
  const float* bb[3] = {(const float*)d_in[7], (const float*)d_in[11], (const float*)d_in[15]};
  const float* res_W = (const float*)d_in[16];
  const float* res_b = (const float*)d_in[17];
  const float* mlp_W1 = (const float*)d_in[18];
  const float* mlp_b1 = (const float*)d_in[19];
  const float* mlp_W2 = (const float*)d_in[20];
  const float* mlp_b2 = (const float*)d_in[21];
  float* out = (float*)d_out;

  const int Ns[4] = {60000, 30000, 15000, 8000};
  int Es[3];
  for (int l = 0; l < 3; ++l) Es[l] = in_sizes[1 + l] / 2;
  int Etot = Es[0] + Es[1] + Es[2];

  char* ws = (char*)d_ws;
  size_t off = 0;
  auto alloc = [&](size_t bytes) { size_t r = off; off += (bytes + 255) & ~(size_t)255; return r; };
  short* Bt[3];
  Bt[0] = (short*)(ws + alloc(512 * 1024 * 2));
  Bt[1] = (short*)(ws + alloc(512 * 1024 * 2));
  Bt[2] = (short*)(ws + alloc(512 * 1024 * 2));
  short* Rt = (short*)(ws + alloc(512 * 512 * 2));
  short* W1t = (short*)(ws + alloc(512 * 2048 * 2));
  short* W2t = (short*)(ws + alloc(256 * 512 * 2));
  const int dbase[3] = {0, 30001, 45002};
  const int ndeg = 53003;
  int ebase[3] = {0, Es[0], Es[0] + Es[1]};
  int* deg3 = (int*)(ws + alloc((size_t)ndeg * 4));
  int* offs3 = (int*)(ws + alloc((size_t)ndeg * 4));
  int* cursor3 = (int*)(ws + alloc((size_t)ndeg * 4));
  int* csr3 = (int*)(ws + alloc((size_t)Etot * 4));
  float* stats3 = (float*)(ws + alloc(3 * 1024 * 4));
  short* xb0 = (short*)(ws + alloc((size_t)60000 * 512 * 2));
  short* x1b = (short*)(ws + alloc((size_t)30000 * 512 * 2));
  short* x2b = (short*)(ws + alloc((size_t)15000 * 512 * 2));
  short* x3b = (short*)(ws + alloc((size_t)8000 * 512 * 2));
  short* Abuf = (short*)(ws + alloc((size_t)30000 * 512 * 2));
  short* h = (short*)(ws + alloc((size_t)30000 * 512 * 2));
  size_t scr_off = alloc((size_t)30000 * 512 * 2);
  short* rbuf = (short*)(ws + scr_off);
  short* z1b = (short*)(ws + scr_off);

  // ---- prep: x0 conversion (first) + zeroing + weight transposes ----
  PrepArgs P;
  P.d[0] = {Wl[0], Bt[0], 1024, 0, 512};
  P.d[1] = {Wr[0], Bt[0], 1024, 512, 512};
  P.d[2] = {Wl[1], Bt[1], 1024, 0, 512};
  P.d[3] = {Wr[1], Bt[1], 1024, 512, 512};
  P.d[4] = {Wl[2], Bt[2], 1024, 0, 512};
  P.d[5] = {Wr[2], Bt[2], 1024, 512, 512};
  P.d[6] = {res_W, Rt, 512, 0, 512};
  P.d[7] = {mlp_W1 + 0 * 512 * 512, W1t, 2048, 0, 512};
  P.d[8] = {mlp_W1 + 1 * 512 * 512, W1t, 2048, 512, 512};
  P.d[9] = {mlp_W1 + 2 * 512 * 512, W1t, 2048, 1024, 512};
  P.d[10] = {mlp_W1 + 3 * 512 * 512, W1t, 2048, 1536, 512};
  P.d[11] = {mlp_W2, W2t, 512, 0, 256};
  P.x0 = x0; P.xb0 = xb0; P.n8 = 60000 * 512 / 8;
  P.deg = deg3; P.cursor = cursor3; P.ndeg = ndeg;
  P.stats = stats3; P.nstats = 3 * 1024;
  prep_kernel<<<dim3(16, 16, 21), 256, 0, stream>>>(P);

  // ---- CSR build ----
  L3s L;
  for (int l = 0; l < 3; ++l) {
    L.ei[l] = eis[l]; L.E[l] = Es[l]; L.dbase[l] = dbase[l]; L.ebase[l] = ebase[l];
  }
  deg_all_kernel<<<dim3((Etot + 255) / 256), 256, 0, stream>>>(L, deg3);
  L3s Ln = L;
  Ln.E[0] = Ns[1]; Ln.E[1] = Ns[2]; Ln.E[2] = Ns[3];
  scan_all_kernel<<<dim3(3), 256, 0, stream>>>(Ln, deg3, offs3);
  fill_all_kernel<<<dim3((Etot + 255) / 256), 256, 0, stream>>>(L, offs3, cursor3, csr3);

  const short* xin[3] = {xb0, x1b, x2b};
  short* xout[3] = {x1b, x2b, x3b};

  auto gblocks = [](int gm, int gn) { return ((gm + 7) / 8) * 8 * gn; };

  for (int l = 0; l < 3; ++l) {
    int n_dst = Ns[l + 1];
    float* stats = stats3 + l * 1024;
    aggregate_kernel<<<dim3((n_dst + 3) / 4), 256, 0, stream>>>(
        xin[l], csr3 + ebase[l], offs3 + dbase[l], Abuf, n_dst);
    if (l == 0) {
      // Merged sage + res (independent; res backfills sage's tail).
      int gm = (n_dst + 127) / 128;
      int nb0 = gblocks(gm, 4);
      G128 dsage = {Abuf, xin[l], Bt[l], 1024, h, nullptr, 512,
                    n_dst, 1024, nullptr, stats, gm, 4};
      G128 dres  = {xin[l], nullptr, Rt, 512, rbuf, nullptr, 512,
                    n_dst, 512, nullptr, nullptr, gm, 4};
      gemm128_dual_kernel<<<dim3(nb0 + gblocks(gm, 4)), 256, 0, stream>>>(
          dsage, dres, nb0);
    } else {
      int gm = (n_dst + 63) / 64;
      sage_gemm64_kernel<<<dim3(gblocks(gm, 4)), 256, 0, stream>>>(
          Abuf, xin[l], nullptr, nullptr, Bt[l], 1024, h, nullptr, 512, n_dst, 1024,
          nullptr, stats, gm, 4);
    }
    apply_kernel<<<dim3(n_dst), 128, 0, stream>>>(h, stats, gg[l], bb[l],
                                                  l == 0 ? rbuf : nullptr, res_b,
                                                  xin[l], xout[l], n_dst, 1.0f / n_dst);
  }

  // ---- head: W1 GEMM, then fused W2+log_softmax ----
  {
    int gm = (8000 + 63) / 64;  // 125
    sage_gemm64_kernel<<<dim3(gblocks(gm, 4)), 256, 0, stream>>>(
        xb0, x1b, x2b, x3b, W1t, 2048, z1b, nullptr, 512, 8000, 2048, mlp_b1,
        nullptr, gm, 4);
    head2_kernel<<<dim3(125), 256, 0, stream>>>(z1b, W2t, mlp_b2, out);
  }
}

// Round 12
// 430.733 us; speedup vs baseline: 1.0467x; 1.0467x over previous
//
#include <hip/hip_runtime.h>

typedef __attribute__((ext_vector_type(8))) short bf16x8;
typedef __attribute__((ext_vector_type(4))) float f32x4;

static __device__ __forceinline__ short f2bf(float f) {
  union { float f; unsigned u; } v; v.f = f;
  unsigned r = v.u + 0x7fffu + ((v.u >> 16) & 1u);
  return (short)(r >> 16);
}
static __device__ __forceinline__ float bf2f(short s) {
  union { unsigned u; float f; } v; v.u = ((unsigned)(unsigned short)s) << 16;
  return v.f;
}

#define GLOBAL_AS(p) ((const __attribute__((address_space(1))) void*)(p))
#define LDS_AS(p)    ((__attribute__((address_space(3))) void*)(p))

struct L3s { const int* ei[3]; int E[3]; int dbase[3]; int ebase[3]; };

// ---------------------------------------------------------------------------
// Tiny zero pass (deg/cursor/stats) so the deg count can run inside prep.
__global__ void zero_kernel(int* __restrict__ deg, int* __restrict__ cursor,
                            float* __restrict__ stats, int ndeg, int nstats) {
  int base = blockIdx.x * 256 + threadIdx.x;
  for (int i = base; i < ndeg; i += 16384) { deg[i] = 0; cursor[i] = 0; }
  for (int i = base; i < nstats; i += 16384) stats[i] = 0.f;
}

// ---------------------------------------------------------------------------
// Batched prep (R10's fused-deg variant: measured -5.5us vs separate deg
// dispatch via the R10/R11 attribution matrix).
// z<8: BW-bound x0 conversion (launches first, saturates HBM);
// z in [8,17): edge-degree count (atomics, hides under conversion);
// z>=17: tiny latency-bound weight transposes backfill as conversion retires.
struct WD { const float* W; short* Wt; int ldt; int koff; int Nn; };
struct PrepArgs {
  WD d[12];
  const float* x0; short* xb0; int n8;
  int* deg; L3s L;
};

__global__ void prep_kernel(PrepArgs P) {
  int z = blockIdx.z;
  if (z < 8) {
    int gtid = (z * 256 + blockIdx.y * 16 + blockIdx.x) * 256 + threadIdx.x;
    int wv = gtid >> 6, lane = gtid & 63;
    const float4* __restrict__ src = (const float4*)P.x0;
    short4* __restrict__ dst = (short4*)P.xb0;
    int n4 = P.n8 * 2;
    for (int b = wv * 128 + lane; b < n4; b += 1048576) {
      float4 a = src[b];
      float4 c = src[b + 64];
      short4 o1; o1.x = f2bf(a.x); o1.y = f2bf(a.y); o1.z = f2bf(a.z); o1.w = f2bf(a.w);
      short4 o2; o2.x = f2bf(c.x); o2.y = f2bf(c.y); o2.z = f2bf(c.z); o2.w = f2bf(c.w);
      dst[b] = o1;
      dst[b + 64] = o2;
    }
  } else if (z < 17) {
    int g = (z - 8) * 65536 + (blockIdx.y * 16 + blockIdx.x) * 256 + threadIdx.x;
    int l = 0, e = g;
    while (l < 3 && e >= P.L.E[l]) { e -= P.L.E[l]; ++l; }
    if (l >= 3) return;
    int d = P.L.ei[l][P.L.E[l] + e];
    atomicAdd(&P.deg[P.L.dbase[l] + d], 1);
  } else {
    __shared__ float tile[32][33];
    const WD dd = P.d[z - 17];
    int kb = blockIdx.x * 32, nb = blockIdx.y * 32;
    if (nb >= dd.Nn) return;
    int tx = threadIdx.x & 31, ty = threadIdx.x >> 5;
#pragma unroll
    for (int j = 0; j < 4; ++j) {
      int k = kb + ty + 8 * j;
      tile[ty + 8 * j][tx] = dd.W[(size_t)k * dd.Nn + nb + tx];
    }
    __syncthreads();
#pragma unroll
    for (int j = 0; j < 4; ++j) {
      int n = nb + ty + 8 * j;
      dd.Wt[(size_t)n * dd.ldt + dd.koff + kb + tx] = f2bf(tile[tx][ty + 8 * j]);
    }
  }
}

// ---------------------------------------------------------------------------
__global__ void scan_all_kernel(L3s Ln, const int* __restrict__ deg, int* __restrict__ offs) {
  __shared__ int sums[257];
  int l = blockIdx.x;
  int n = Ln.E[l];
  const int* dg = deg + Ln.dbase[l];
  int* of = offs + Ln.dbase[l];
  int t = threadIdx.x;
  int per = (n + 255) / 256;
  int b = t * per, e = min(b + per, n);
  int s = 0;
  for (int i = b; i < e; ++i) s += dg[i];
  sums[t] = s;
  __syncthreads();
  if (t == 0) {
    int acc = 0;
    for (int i = 0; i < 256; ++i) { int v = sums[i]; sums[i] = acc; acc += v; }
    sums[256] = acc;
  }
  __syncthreads();
  int acc = sums[t];
  for (int i = b; i < e; ++i) { of[i] = acc; acc += dg[i]; }
  if (t == 255) of[n] = sums[256];
}

__global__ void fill_all_kernel(L3s L, const int* __restrict__ offs,
                                int* __restrict__ cursor, int* __restrict__ csr) {
  int g = blockIdx.x * 256 + threadIdx.x;
  int l = 0, e = g;
  while (l < 3 && e >= L.E[l]) { e -= L.E[l]; ++l; }
  if (l >= 3) return;
  int d = L.ei[l][L.E[l] + e];
  int p = atomicAdd(&cursor[L.dbase[l] + d], 1);
  csr[L.ebase[l] + offs[L.dbase[l] + d] + p] = L.ei[l][e];
}

// ---------------------------------------------------------------------------
// Gather aggregation, wave-per-node, 4-deep unroll. Mean half only.
__global__ void aggregate_kernel(const short* __restrict__ xb, const int* __restrict__ csr,
                                 const int* __restrict__ offs, short* __restrict__ A,
                                 int n_dst) {
  int node = blockIdx.x * 4 + (threadIdx.x >> 6);
  if (node >= n_dst) return;
  int lane = threadIdx.x & 63;
  const short* xp = xb + lane * 8;
  int s0 = offs[node], s1 = offs[node + 1];
  float a[8];
#pragma unroll
  for (int j = 0; j < 8; ++j) a[j] = 0.f;
  int e = s0;
  for (; e + 3 < s1; e += 4) {
    bf16x8 v0 = *(const bf16x8*)(xp + (size_t)csr[e] * 512);
    bf16x8 v1 = *(const bf16x8*)(xp + (size_t)csr[e + 1] * 512);
    bf16x8 v2 = *(const bf16x8*)(xp + (size_t)csr[e + 2] * 512);
    bf16x8 v3 = *(const bf16x8*)(xp + (size_t)csr[e + 3] * 512);
#pragma unroll
    for (int j = 0; j < 8; ++j) a[j] += (bf2f(v0[j]) + bf2f(v1[j])) + (bf2f(v2[j]) + bf2f(v3[j]));
  }
  for (; e < s1; ++e) {
    bf16x8 v0 = *(const bf16x8*)(xp + (size_t)csr[e] * 512);
#pragma unroll
    for (int j = 0; j < 8; ++j) a[j] += bf2f(v0[j]);
  }
  float inv = (s1 > s0) ? 1.0f / (float)(s1 - s0) : 0.0f;
  bf16x8 o;
#pragma unroll
  for (int j = 0; j < 8; ++j) o[j] = f2bf(a[j] * inv);
  *(bf16x8*)(A + (size_t)node * 512 + lane * 8) = o;
}

// ---------------------------------------------------------------------------
// 128x128 GEMM with dual-descriptor dispatch (layer-0 sage + res share one
// grid; res backfills sage's block-quantization tail).
struct G128 {
  const short* Am; const short* Ax;
  const short* Bt; int ldb;
  short* hC; float* fC; int ldc;
  int M; int K;
  const float* bias; float* stats;
  int gm; int gn;
};

__global__ __launch_bounds__(256, 4)
void gemm128_dual_kernel(G128 d0, G128 d1, int nb0) {
  __shared__ short lds[16384];
  short* As = lds;
  short* Bs = lds + 8192;
  const bool second = (int)blockIdx.x >= nb0;
  const G128& D = second ? d1 : d0;
  const int id = (int)blockIdx.x - (second ? nb0 : 0);
  const int g = id >> 3;
  const int bn = g % D.gn;
  const int bm = (g / D.gn) * 8 + (id & 7);
  if (bm >= D.gm) return;
  const int tid = threadIdx.x;
  const int wid = tid >> 6;
  const int lane = tid & 63;
  const int lm = lane & 15;
  const int quad = lane >> 4;
  const int wr = wid >> 1, wc = wid & 1;
  const int srow = lane >> 3;
  const int kswz = (((lane & 7) ^ srow) << 3);
  const int M = D.M;

  f32x4 acc[4][4];
#pragma unroll
  for (int i = 0; i < 4; ++i)
#pragma unroll
    for (int j = 0; j < 4; ++j) acc[i][j] = (f32x4)0.f;

  for (int k0 = 0; k0 < D.K; k0 += 64) {
    const short* Aptr = (k0 < 512) ? D.Am : D.Ax;
    int kloc = k0 & 511;
#pragma unroll
    for (int j = 0; j < 4; ++j) {
      int ch = wid * 4 + j;
      int arow = bm * 128 + ch * 8 + srow;
      arow = arow < M ? arow : M - 1;
      const short* ga = Aptr + (size_t)arow * 512 + kloc + kswz;
      __builtin_amdgcn_global_load_lds(GLOBAL_AS(ga), LDS_AS(As + ch * 512), 16, 0, 0);
      int brow = bn * 128 + ch * 8 + srow;
      const short* gb = D.Bt + (size_t)brow * D.ldb + k0 + kswz;
      __builtin_amdgcn_global_load_lds(GLOBAL_AS(gb), LDS_AS(Bs + ch * 512), 16, 0, 0);
    }
    __syncthreads();
#pragma unroll
    for (int ks = 0; ks < 2; ++ks) {
      bf16x8 af[4], bfr[4];
      int xo = ((ks * 4 + quad) ^ (lm & 7)) * 8;
#pragma unroll
      for (int mi = 0; mi < 4; ++mi)
        af[mi] = *(const bf16x8*)(As + (wr * 64 + mi * 16 + lm) * 64 + xo);
#pragma unroll
      for (int ni = 0; ni < 4; ++ni)
        bfr[ni] = *(const bf16x8*)(Bs + (wc * 64 + ni * 16 + lm) * 64 + xo);
#pragma unroll
      for (int mi = 0; mi < 4; ++mi)
#pragma unroll
        for (int ni = 0; ni < 4; ++ni)
          acc[mi][ni] = __builtin_amdgcn_mfma_f32_16x16x32_bf16(af[mi], bfr[ni], acc[mi][ni], 0, 0, 0);
    }
    __syncthreads();
  }

#pragma unroll
  for (int mi = 0; mi < 4; ++mi) {
#pragma unroll
    for (int ni = 0; ni < 4; ++ni) {
      int gcol = bn * 128 + wc * 64 + ni * 16 + lm;
      float bv = D.bias ? D.bias[gcol] : 0.f;
#pragma unroll
      for (int r2 = 0; r2 < 4; ++r2) {
        int grow = bm * 128 + wr * 64 + mi * 16 + quad * 4 + r2;
        if (grow < M) {
          float val = acc[mi][ni][r2] + bv;
          if (D.hC) D.hC[(size_t)grow * D.ldc + gcol] = f2bf(val);
          else      D.fC[(size_t)grow * D.ldc + gcol] = val;
        }
      }
    }
  }

  if (D.stats) {
    float* s1 = (float*)lds;
    float* s2 = s1 + 128;
    if (tid < 128) { s1[tid] = 0.f; s2[tid] = 0.f; }
    __syncthreads();
#pragma unroll
    for (int ni = 0; ni < 4; ++ni) {
      int cloc = wc * 64 + ni * 16 + lm;
      float p1 = 0.f, p2 = 0.f;
#pragma unroll
      for (int mi = 0; mi < 4; ++mi)
#pragma unroll
        for (int r2 = 0; r2 < 4; ++r2) {
          int grow = bm * 128 + wr * 64 + mi * 16 + quad * 4 + r2;
          if (grow < M) {
            float v = acc[mi][ni][r2];
            p1 += v; p2 += v * v;
          }
        }
      atomicAdd(&s1[cloc], p1);
      atomicAdd(&s2[cloc], p2);
    }
    __syncthreads();
    if (tid < 128) {
      int gcol = bn * 128 + tid;
      atomicAdd(&D.stats[gcol], s1[tid]);
      atomicAdd(&D.stats[512 + gcol], s2[tid]);
    }
  }
}

// ---------------------------------------------------------------------------
// BM=64 GEMM for small-M dispatches (M<=15000).
__global__ __launch_bounds__(256, 4)
void sage_gemm64_kernel(const short* __restrict__ A0, const short* __restrict__ A1,
                        const short* __restrict__ A2, const short* __restrict__ A3,
                        const short* __restrict__ Bt, int ldb,
                        short* __restrict__ hC, float* __restrict__ fC, int ldc,
                        int M, int K, const float* __restrict__ bias,
                        float* __restrict__ stats, int gm, int gn) {
  __shared__ short lds[12288];   // As 64x64 (8KB) + Bs 128x64 (16KB)
  short* As = lds;
  short* Bs = lds + 4096;
  const int id = blockIdx.x;
  const int g = id >> 3;
  const int bn = g % gn;
  const int bm = (g / gn) * 8 + (id & 7);
  if (bm >= gm) return;
  const int tid = threadIdx.x;
  const int wid = tid >> 6;
  const int lane = tid & 63;
  const int lm = lane & 15;
  const int quad = lane >> 4;
  const int srow = lane >> 3;
  const int kswz = (((lane & 7) ^ srow) << 3);
  const short* Aps[4] = {A0, A1, A2, A3};

  f32x4 acc[4][2];
#pragma unroll
  for (int i = 0; i < 4; ++i)
#pragma unroll
    for (int j = 0; j < 2; ++j) acc[i][j] = (f32x4)0.f;

  for (int k0 = 0; k0 < K; k0 += 64) {
    const short* Aptr = Aps[k0 >> 9];
    int kloc = k0 & 511;
#pragma unroll
    for (int j = 0; j < 6; ++j) {
      int ch = wid * 6 + j;
      if (ch < 8) {
        int arow = bm * 64 + ch * 8 + srow;
        arow = arow < M ? arow : M - 1;
        const short* ga = Aptr + (size_t)arow * 512 + kloc + kswz;
        __builtin_amdgcn_global_load_lds(GLOBAL_AS(ga), LDS_AS(As + ch * 512), 16, 0, 0);
      } else {
        int bc = ch - 8;
        int brow = bn * 128 + bc * 8 + srow;
        const short* gb = Bt + (size_t)brow * ldb + k0 + kswz;
        __builtin_amdgcn_global_load_lds(GLOBAL_AS(gb), LDS_AS(Bs + bc * 512), 16, 0, 0);
      }
    }
    __syncthreads();
#pragma unroll
    for (int ks = 0; ks < 2; ++ks) {
      bf16x8 af[4], bfr[2];
      int xo = ((ks * 4 + quad) ^ (lm & 7)) * 8;
#pragma unroll
      for (int mi = 0; mi < 4; ++mi)
        af[mi] = *(const bf16x8*)(As + (mi * 16 + lm) * 64 + xo);
#pragma unroll
      for (int ni = 0; ni < 2; ++ni)
        bfr[ni] = *(const bf16x8*)(Bs + (wid * 32 + ni * 16 + lm) * 64 + xo);
#pragma unroll
      for (int mi = 0; mi < 4; ++mi)
#pragma unroll
        for (int ni = 0; ni < 2; ++ni)
          acc[mi][ni] = __builtin_amdgcn_mfma_f32_16x16x32_bf16(af[mi], bfr[ni], acc[mi][ni], 0, 0, 0);
    }
    __syncthreads();
  }

#pragma unroll
  for (int mi = 0; mi < 4; ++mi) {
#pragma unroll
    for (int ni = 0; ni < 2; ++ni) {
      int gcol = bn * 128 + wid * 32 + ni * 16 + lm;
      float bv = bias ? bias[gcol] : 0.f;
#pragma unroll
      for (int r2 = 0; r2 < 4; ++r2) {
        int grow = bm * 64 + mi * 16 + quad * 4 + r2;
        if (grow < M) {
          float val = acc[mi][ni][r2] + bv;
          if (hC) hC[(size_t)grow * ldc + gcol] = f2bf(val);
          else    fC[(size_t)grow * ldc + gcol] = val;
        }
      }
    }
  }

  if (stats) {
    float* s1 = (float*)lds;
    float* s2 = s1 + 128;
    if (tid < 128) { s1[tid] = 0.f; s2[tid] = 0.f; }
    __syncthreads();
#pragma unroll
    for (int ni = 0; ni < 2; ++ni) {
      int cloc = wid * 32 + ni * 16 + lm;
      float p1 = 0.f, p2 = 0.f;
#pragma unroll
      for (int mi = 0; mi < 4; ++mi)
#pragma unroll
        for (int r2 = 0; r2 < 4; ++r2) {
          int grow = bm * 64 + mi * 16 + quad * 4 + r2;
          if (grow < M) {
            float v = acc[mi][ni][r2];
            p1 += v; p2 += v * v;
          }
        }
      atomicAdd(&s1[cloc], p1);
      atomicAdd(&s2[cloc], p2);
    }
    __syncthreads();
    if (tid < 128) {
      int gcol = bn * 128 + tid;
      atomicAdd(&stats[gcol], s1[tid]);
      atomicAdd(&stats[512 + gcol], s2[tid]);
    }
  }
}

// ---------------------------------------------------------------------------
// x_out(bf16) = leaky(BN(h_bf16; stats)) + (rbuf_bf16 + res_b | xdst_bf16).
__global__ void apply_kernel(const short* __restrict__ h, const float* __restrict__ stats,
                             const float* __restrict__ g, const float* __restrict__ b,
                             const short* __restrict__ r, const float* __restrict__ res_b,
                             const short* __restrict__ xdst, short* __restrict__ outp,
                             int n, float inv_n) {
  int i = blockIdx.x;
  int c = threadIdx.x * 4;
  short4 hb = *(const short4*)(h + (size_t)i * 512 + c);
  float4 s1 = *(const float4*)(stats + c);
  float4 s2 = *(const float4*)(stats + 512 + c);
  float4 gv = *(const float4*)(g + c);
  float4 bv = *(const float4*)(b + c);
  float mux = s1.x * inv_n, muy = s1.y * inv_n, muz = s1.z * inv_n, muw = s1.w * inv_n;
  float rsx = rsqrtf(s2.x * inv_n - mux * mux + 1e-5f);
  float rsy = rsqrtf(s2.y * inv_n - muy * muy + 1e-5f);
  float rsz = rsqrtf(s2.z * inv_n - muz * muz + 1e-5f);
  float rsw = rsqrtf(s2.w * inv_n - muw * muw + 1e-5f);
  float4 o;
  o.x = (bf2f(hb.x) - mux) * rsx * gv.x + bv.x;
  o.y = (bf2f(hb.y) - muy) * rsy * gv.y + bv.y;
  o.z = (bf2f(hb.z) - muz) * rsz * gv.z + bv.z;
  o.w = (bf2f(hb.w) - muw) * rsw * gv.w + bv.w;
  o.x = o.x >= 0.f ? o.x : 0.01f * o.x;
  o.y = o.y >= 0.f ? o.y : 0.01f * o.y;
  o.z = o.z >= 0.f ? o.z : 0.01f * o.z;
  o.w = o.w >= 0.f ? o.w : 0.01f * o.w;
  if (r) {
    short4 rv = *(const short4*)(r + (size_t)i * 512 + c);
    float4 rb = *(const float4*)(res_b + c);
    o.x += bf2f(rv.x) + rb.x; o.y += bf2f(rv.y) + rb.y;
    o.z += bf2f(rv.z) + rb.z; o.w += bf2f(rv.w) + rb.w;
  } else {
    short4 xv = *(const short4*)(xdst + (size_t)i * 512 + c);
    o.x += bf2f(xv.x); o.y += bf2f(xv.y); o.z += bf2f(xv.z); o.w += bf2f(xv.w);
  }
  short4 ov;
  ov.x = f2bf(o.x); ov.y = f2bf(o.y); ov.z = f2bf(o.z); ov.w = f2bf(o.w);
  *(short4*)(outp + (size_t)i * 512 + c) = ov;
}

// ---------------------------------------------------------------------------
__global__ void lsm_kernel(const float* __restrict__ z, float* __restrict__ outp) {
  __shared__ float redm[4], reds[4];
  int row = blockIdx.x, t = threadIdx.x;
  float v = z[(size_t)row * 256 + t];
  float m = v;
#pragma unroll
  for (int o = 32; o >= 1; o >>= 1) m = fmaxf(m, __shfl_down(m, o, 64));
  if ((t & 63) == 0) redm[t >> 6] = m;
  __syncthreads();
  m = fmaxf(fmaxf(redm[0], redm[1]), fmaxf(redm[2], redm[3]));
  float e = __expf(v - m);
  float s = e;
#pragma unroll
  for (int o = 32; o >= 1; o >>= 1) s += __shfl_down(s, o, 64);
  if ((t & 63) == 0) reds[t >> 6] = s;
  __syncthreads();
  s = reds[0] + reds[1] + reds[2] + reds[3];
  outp[(size_t)row * 256 + t] = v - m - __logf(s);
}

// ---------------------------------------------------------------------------
extern "C" void kernel_launch(void* const* d_in, const int* in_sizes, int n_in,
                              void* d_out, int out_size, void* d_ws, size_t ws_size,
                              hipStream_t stream) {
  const float* x0 = (const float*)d_in[0];
  const int* eis[3] = {(const int*)d_in[1], (const int*)d_in[2], (const int*)d_in[3]};
  const float* Wl[3] = {(const float*)d_in[4], (const float*)d_in[8], (const float*)d_in[12]};
  const float* Wr[3] = {(const float*)d_in[5], (const float*)d_in[9], (const float*)d_in[13]};
  const float* gg[3] = {(const float*)d_in[6], (const float*)d_in[10], (const float*)d_in[14]};
  const float* bb[3] = {(const float*)d_in[7], (const float*)d_in[11], (const float*)d_in[15]};
  const float* res_W = (const float*)d_in[16];
  const float* res_b = (const float*)d_in[17];
  const float* mlp_W1 = (const float*)d_in[18];
  const float* mlp_b1 = (const float*)d_in[19];
  const float* mlp_W2 = (const float*)d_in[20];
  const float* mlp_b2 = (const float*)d_in[21];
  float* out = (float*)d_out;

  const int Ns[4] = {60000, 30000, 15000, 8000};
  int Es[3];
  for (int l = 0; l < 3; ++l) Es[l] = in_sizes[1 + l] / 2;
  int Etot = Es[0] + Es[1] + Es[2];

  char* ws = (char*)d_ws;
  size_t off = 0;
  auto alloc = [&](size_t bytes) { size_t r = off; off += (bytes + 255) & ~(size_t)255; return r; };
  short* Bt[3];
  Bt[0] = (short*)(ws + alloc(512 * 1024 * 2));
  Bt[1] = (short*)(ws + alloc(512 * 1024 * 2));
  Bt[2] = (short*)(ws + alloc(512 * 1024 * 2));
  short* Rt = (short*)(ws + alloc(512 * 512 * 2));
  short* W1t = (short*)(ws + alloc(512 * 2048 * 2));
  short* W2t = (short*)(ws + alloc(256 * 512 * 2));
  const int dbase[3] = {0, 30001, 45002};
  const int ndeg = 53003;
  int ebase[3] = {0, Es[0], Es[0] + Es[1]};
  int* deg3 = (int*)(ws + alloc((size_t)ndeg * 4));
  int* offs3 = (int*)(ws + alloc((size_t)ndeg * 4));
  int* cursor3 = (int*)(ws + alloc((size_t)ndeg * 4));
  int* csr3 = (int*)(ws + alloc((size_t)Etot * 4));
  float* stats3 = (float*)(ws + alloc(3 * 1024 * 4));
  short* xb0 = (short*)(ws + alloc((size_t)60000 * 512 * 2));
  short* x1b = (short*)(ws + alloc((size_t)30000 * 512 * 2));
  short* x2b = (short*)(ws + alloc((size_t)15000 * 512 * 2));
  short* x3b = (short*)(ws + alloc((size_t)8000 * 512 * 2));
  short* Abuf = (short*)(ws + alloc((size_t)30000 * 512 * 2));
  short* h = (short*)(ws + alloc((size_t)30000 * 512 * 2));
  size_t scr_off = alloc((size_t)30000 * 512 * 2);
  short* rbuf = (short*)(ws + scr_off);
  short* z1b = (short*)(ws + scr_off);
  float* z2 = (float*)(ws + alloc((size_t)8000 * 256 * 4));

  L3s L;
  for (int l = 0; l < 3; ++l) {
    L.ei[l] = eis[l]; L.E[l] = Es[l]; L.dbase[l] = dbase[l]; L.ebase[l] = ebase[l];
  }

  // ---- zero (deg/cursor/stats), then prep with deg fused as z-slices ----
  zero_kernel<<<dim3(64), 256, 0, stream>>>(deg3, cursor3, stats3, ndeg, 3 * 1024);

  PrepArgs P;
  P.d[0] = {Wl[0], Bt[0], 1024, 0, 512};
  P.d[1] = {Wr[0], Bt[0], 1024, 512, 512};
  P.d[2] = {Wl[1], Bt[1], 1024, 0, 512};
  P.d[3] = {Wr[1], Bt[1], 1024, 512, 512};
  P.d[4] = {Wl[2], Bt[2], 1024, 0, 512};
  P.d[5] = {Wr[2], Bt[2], 1024, 512, 512};
  P.d[6] = {res_W, Rt, 512, 0, 512};
  P.d[7] = {mlp_W1 + 0 * 512 * 512, W1t, 2048, 0, 512};
  P.d[8] = {mlp_W1 + 1 * 512 * 512, W1t, 2048, 512, 512};
  P.d[9] = {mlp_W1 + 2 * 512 * 512, W1t, 2048, 1024, 512};
  P.d[10] = {mlp_W1 + 3 * 512 * 512, W1t, 2048, 1536, 512};
  P.d[11] = {mlp_W2, W2t, 512, 0, 256};
  P.x0 = x0; P.xb0 = xb0; P.n8 = 60000 * 512 / 8;
  P.deg = deg3; P.L = L;
  prep_kernel<<<dim3(16, 16, 29), 256, 0, stream>>>(P);

  // ---- CSR: scan + fill ----
  L3s Ln = L;
  Ln.E[0] = Ns[1]; Ln.E[1] = Ns[2]; Ln.E[2] = Ns[3];
  scan_all_kernel<<<dim3(3), 256, 0, stream>>>(Ln, deg3, offs3);
  fill_all_kernel<<<dim3((Etot + 255) / 256), 256, 0, stream>>>(L, offs3, cursor3, csr3);

  const short* xin[3] = {xb0, x1b, x2b};
  short* xout[3] = {x1b, x2b, x3b};

  auto gblocks = [](int gm, int gn) { return ((gm + 7) / 8) * 8 * gn; };

  for (int l = 0; l < 3; ++l) {
    int n_dst = Ns[l + 1];
    float* stats = stats3 + l * 1024;
    aggregate_kernel<<<dim3((n_dst + 3) / 4), 256, 0, stream>>>(
        xin[l], csr3 + ebase[l], offs3 + dbase[l], Abuf, n_dst);
    if (l == 0) {
      // Merged sage + res (independent; res backfills sage's tail).
      int gm = (n_dst + 127) / 128;
      int nb0 = gblocks(gm, 4);
      G128 dsage = {Abuf, xin[l], Bt[l], 1024, h, nullptr, 512,
                    n_dst, 1024, nullptr, stats, gm, 4};
      G128 dres  = {xin[l], nullptr, Rt, 512, rbuf, nullptr, 512,
                    n_dst, 512, nullptr, nullptr, gm, 4};
      gemm128_dual_kernel<<<dim3(nb0 + gblocks(gm, 4)), 256, 0, stream>>>(
          dsage, dres, nb0);
    } else {
      int gm = (n_dst + 63) / 64;
      sage_gemm64_kernel<<<dim3(gblocks(gm, 4)), 256, 0, stream>>>(
          Abuf, xin[l], nullptr, nullptr, Bt[l], 1024, h, nullptr, 512, n_dst, 1024,
          nullptr, stats, gm, 4);
    }
    apply_kernel<<<dim3(n_dst), 128, 0, stream>>>(h, stats, gg[l], bb[l],
                                                  l == 0 ? rbuf : nullptr, res_b,
                                                  xin[l], xout[l], n_dst, 1.0f / n_dst);
  }

  // ---- head: W1 GEMM, W2 GEMM, log-softmax (R9's proven path) ----
  {
    int gm = (8000 + 63) / 64;  // 125
    sage_gemm64_kernel<<<dim3(gblocks(gm, 4)), 256, 0, stream>>>(
        xb0, x1b, x2b, x3b, W1t, 2048, z1b, nullptr, 512, 8000, 2048, mlp_b1,
        nullptr, gm, 4);
    sage_gemm64_kernel<<<dim3(gblocks(gm, 2)), 256, 0, stream>>>(
        z1b, nullptr, nullptr, nullptr, W2t, 512, nullptr, z2, 256, 8000, 512,
        mlp_b2, nullptr, gm, 2);
  }
  lsm_kernel<<<dim3(8000), 256, 0, stream>>>(z2, out);
}